// Round 8
// baseline (226.920 us; speedup 1.0000x reference)
//
#include <hip/hip_runtime.h>
#include <stdint.h>

typedef unsigned short u16;
typedef __attribute__((ext_vector_type(8))) short short8;
typedef __attribute__((ext_vector_type(4))) float floatx4;
typedef __attribute__((ext_vector_type(2))) float floatx2;

#define K_DIM 1024
#define N_DIM 1024
#define BK 32
#define NCHUNK 32
#define GCH 2             // chunks per pipeline group
#define NGRP (NCHUNK / GCH)
// fallback kernel params
#define BM 64
#define HCHUNK 16

__device__ __forceinline__ u16 f2b(float f) {
    union { float f; uint32_t i; } v; v.f = f;
    uint32_t u = v.i;
    return (u16)((u + 0x7FFFu + ((u >> 16) & 1u)) >> 16);   // RNE fp32->bf16
}
__device__ __forceinline__ float b2f(u16 u) {
    union { uint32_t i; float f; } v; v.i = ((uint32_t)u) << 16; return v.f;
}

// ---------- kernel 1: W fp32 -> bf16, packed in MFMA-fragment order ----------
// packed[(tile*32 + kc)*512 + lane*8 + j] = bf16(W[tile*16 + (lane&15)][kc*32 + (lane>>4)*8 + j])
__global__ __launch_bounds__(256) void pack_w_kernel(const float* __restrict__ w,
                                                     u16* __restrict__ wpk) {
    int gid  = blockIdx.x * 256 + threadIdx.x;
    int lane = gid & 63;
    int kc   = (gid >> 6) & 31;
    int tile = gid >> 11;
    int n = tile * 16 + (lane & 15);
    int k = kc * 32 + (lane >> 4) * 8;
    const float* src = w + (size_t)n * K_DIM + k;
    floatx4 a = *(const floatx4*)(src);
    floatx4 b = *(const floatx4*)(src + 4);
    short8 o;
    o[0] = (short)f2b(a[0]); o[1] = (short)f2b(a[1]);
    o[2] = (short)f2b(a[2]); o[3] = (short)f2b(a[3]);
    o[4] = (short)f2b(b[0]); o[5] = (short)f2b(b[1]);
    o[6] = (short)f2b(b[2]); o[7] = (short)f2b(b[3]);
    *(short8*)(wpk + (size_t)gid * 8) = o;
}

// ---------- kernel 2a: 256x256-tile GEMM + bias + partial row sums + z -------
// Fill-bound fix: per-block line traffic = A 1MB(fp32) + B 0.5MB vs 2.25MB at
// the old 64x1024 tile. 512 threads = 8 waves (wr=wv>>1 in 0..3, wc=wv&1), each
// wave owns 64 rows x 128 cols (acc[4][8] -> 128 AGPR). Double-buffered 2-chunk
// groups: issue next-group global loads into regs, compute, cvt+ds_write, one
// raw barrier (no vmcnt drain). Row stats are PARTIAL (256 cols) -> global
// fp32 atomics; ln_apply finishes mean/rstd.
__global__ __launch_bounds__(512) void gemm256_kernel(
    const float* __restrict__ x, const u16* __restrict__ wpk,
    const float* __restrict__ bias, u16* __restrict__ zout,
    float* __restrict__ gsum, float* __restrict__ gsum2)
{
    // bytes [0,65536): A bufs 2 x (2 x 16KB); [65536,131072): B bufs 2 x (2 x 16KB)
    // zbuf (32KB) aliases bytes [0,32768) after the K-loop.
    __shared__ __align__(16) u16 smem[65536];
    __shared__ float ls_sum[256];
    __shared__ float ls_sum2[256];

    const int tid  = threadIdx.x;
    const int lane = tid & 63;
    const int wv   = tid >> 6;          // 0..7
    const int wr   = wv >> 1;           // 0..3  row-group of wave
    const int wc   = wv & 1;            // 0..1  col-group of wave
    const int q    = lane >> 4;
    const int rb   = blockIdx.x >> 2;   // 0..63
    const int cb   = blockIdx.x & 3;    // 0..3
    const int row0 = rb * 256;
    const int col0 = cb * 256;

    if (tid < 256) { ls_sum[tid] = 0.0f; ls_sum2[tid] = 0.0f; }

    // ---- A staging addressing (verified swizzle, per 64-row 4KB sub-slab) ----
    const int rb8 = tid >> 4;                 // 0..31
    const int sk  = (tid & 15) << 1;          // even 0..30
    const int s_qs  = (sk >> 3) ^ ((rb8 >> 1) & 3);
    const int s_off0 = rb8 * 64 + s_qs * 16 + (sk & 7) * 2;   // row rb8
    const int s_off1 = s_off0 + 2048;                          // row rb8+32 (same qs)
    const float* xb = x + (size_t)(row0 + rb8) * K_DIM + sk;

    // ---- B source base: frag (tile=cb*16+f, kc) at (tile*32+kc)*512 + lane*8 ----
    const u16* wb0 = wpk + ((size_t)(cb * 16 + wv * 2) * 32) * 512 + lane * 8;
    const u16* wb1 = wpk + ((size_t)(cb * 16 + wv * 2 + 1) * 32) * 512 + lane * 8;

    // ---- A fragment LDS offset within a 4KB sub-slab (verified) ----
    const int a_base = (lane & 15) * 64 + (q ^ (((lane & 15) >> 1) & 3)) * 16;

    floatx4 acc[4][8];
#pragma unroll
    for (int mi = 0; mi < 4; ++mi)
#pragma unroll
        for (int ni = 0; ni < 8; ++ni)
            acc[mi][ni] = (floatx4){0.0f, 0.0f, 0.0f, 0.0f};

    // ---- prologue: stage group 0 directly into buf 0 ----
    {
        char* A0 = (char*)smem;
        char* B0 = (char*)smem + 65536;
#pragma unroll
        for (int c2 = 0; c2 < GCH; ++c2) {
#pragma unroll
            for (int j = 0; j < 8; ++j) {
                floatx2 v = *(const floatx2*)(xb + (size_t)((j & 1) * 32 + (j >> 1) * 64) * K_DIM + c2 * BK);
                uint32_t p = (uint32_t)f2b(v[0]) | ((uint32_t)f2b(v[1]) << 16);
                *(uint32_t*)(A0 + c2 * 16384 + (j >> 1) * 4096 + ((j & 1) ? s_off1 : s_off0)) = p;
            }
            short8 t0 = *(const short8*)(wb0 + (size_t)c2 * 512);
            short8 t1 = *(const short8*)(wb1 + (size_t)c2 * 512);
            *(short8*)(B0 + c2 * 16384 + (wv * 2) * 1024 + lane * 16)     = t0;
            *(short8*)(B0 + c2 * 16384 + (wv * 2 + 1) * 1024 + lane * 16) = t1;
        }
    }
    __syncthreads();   // group-0 staging + ls init visible

    floatx2 va[GCH][8];
    short8  bs[GCH][2];

#pragma unroll 1
    for (int g = 0; g < NGRP; ++g) {
        const int cur = g & 1;
        const int nxt = cur ^ 1;
        const bool pf = (g + 1 < NGRP);

        // (1) issue next-group global loads into registers (fly during compute)
        if (pf) {
            const int kb = (g + 1) * GCH;
#pragma unroll
            for (int c2 = 0; c2 < GCH; ++c2) {
#pragma unroll
                for (int j = 0; j < 8; ++j)
                    va[c2][j] = *(const floatx2*)(xb + (size_t)((j & 1) * 32 + (j >> 1) * 64) * K_DIM + (kb + c2) * BK);
                bs[c2][0] = *(const short8*)(wb0 + (size_t)(kb + c2) * 512);
                bs[c2][1] = *(const short8*)(wb1 + (size_t)(kb + c2) * 512);
            }
        }

        // (2) compute 2 chunks from buf[cur]
#pragma unroll
        for (int c2 = 0; c2 < GCH; ++c2) {
            const char* Ab = (const char*)smem + cur * 32768 + c2 * 16384;
            const char* Bb = (const char*)smem + 65536 + cur * 32768 + c2 * 16384;
            short8 af[4];
#pragma unroll
            for (int mi = 0; mi < 4; ++mi)
                af[mi] = *(const short8*)(Ab + wr * 4096 + a_base + mi * 1024);
            short8 bf[8];
#pragma unroll
            for (int ni = 0; ni < 8; ++ni)
                bf[ni] = *(const short8*)(Bb + (wc * 8 + ni) * 1024 + lane * 16);
#pragma unroll
            for (int mi = 0; mi < 4; ++mi)
#pragma unroll
                for (int ni = 0; ni < 8; ++ni)
                    acc[mi][ni] = __builtin_amdgcn_mfma_f32_16x16x32_bf16(
                        af[mi], bf[ni], acc[mi][ni], 0, 0, 0);
        }

        // (3) stage next group into buf[nxt] (regs were loaded in (1))
        if (pf) {
            char* An = (char*)smem + nxt * 32768;
            char* Bn = (char*)smem + 65536 + nxt * 32768;
#pragma unroll
            for (int c2 = 0; c2 < GCH; ++c2) {
#pragma unroll
                for (int j = 0; j < 8; ++j) {
                    uint32_t p = (uint32_t)f2b(va[c2][j][0]) | ((uint32_t)f2b(va[c2][j][1]) << 16);
                    *(uint32_t*)(An + c2 * 16384 + (j >> 1) * 4096 + ((j & 1) ? s_off1 : s_off0)) = p;
                }
                *(short8*)(Bn + c2 * 16384 + (wv * 2) * 1024 + lane * 16)     = bs[c2][0];
                *(short8*)(Bn + c2 * 16384 + (wv * 2 + 1) * 1024 + lane * 16) = bs[c2][1];
            }
        }

        // (4) raw barrier: ds ops drained, global pipeline untouched
        asm volatile("s_waitcnt lgkmcnt(0)" ::: "memory");
        __builtin_amdgcn_s_barrier();
        asm volatile("" ::: "memory");
    }

    // ---- bias ----
    float bias_v[8];
#pragma unroll
    for (int ni = 0; ni < 8; ++ni)
        bias_v[ni] = bias[col0 + wc * 128 + ni * 16 + (lane & 15)];
#pragma unroll
    for (int mi = 0; mi < 4; ++mi)
#pragma unroll
        for (int ni = 0; ni < 8; ++ni)
#pragma unroll
            for (int r = 0; r < 4; ++r)
                acc[mi][ni][r] += bias_v[ni];

    // ---- partial row stats (this block's 256 cols) ----
#pragma unroll
    for (int mi = 0; mi < 4; ++mi)
#pragma unroll
        for (int r = 0; r < 4; ++r) {
            float s = 0.0f, s2 = 0.0f;
#pragma unroll
            for (int ni = 0; ni < 8; ++ni) {
                float v = acc[mi][ni][r];
                s += v; s2 += v * v;
            }
#pragma unroll
            for (int m = 1; m < 16; m <<= 1) {
                s  += __shfl_xor(s,  m, 64);
                s2 += __shfl_xor(s2, m, 64);
            }
            if ((lane & 15) == 0) {
                int rl = wr * 64 + mi * 16 + (q << 2) + r;
                atomicAdd(&ls_sum[rl], s);
                atomicAdd(&ls_sum2[rl], s2);
            }
        }

    __syncthreads();
    if (tid < 256) {
        atomicAdd(&gsum[row0 + tid],  ls_sum[tid]);
        atomicAdd(&gsum2[row0 + tid], ls_sum2[tid]);
    }

    // ---- z store: 4 slices of 64 rows x 256 cols via swizzled LDS transpose ----
    char* zb = (char*)smem;   // 32KB, aliases A buf0 (K-loop done)
    for (int s4 = 0; s4 < 4; ++s4) {
        if (wr == s4) {
#pragma unroll
            for (int mi = 0; mi < 4; ++mi)
#pragma unroll
                for (int ni = 0; ni < 8; ++ni)
#pragma unroll
                    for (int r = 0; r < 4; ++r) {
                        int lr  = mi * 16 + (q << 2) + r;              // 0..63
                        int col = wc * 128 + ni * 16 + (lane & 15);    // 0..255
                        int phys = lr * 512 + ((col << 1) ^ (q << 5));
                        *(u16*)(zb + phys) = f2b(acc[mi][ni][r]);
                    }
        }
        __syncthreads();
#pragma unroll
        for (int it = 0; it < 4; ++it) {
            int row = tid >> 3;                    // 0..63
            int c8  = (tid & 7) + it * 8;          // 0..31
            int phys = row * 512 + ((c8 << 4) ^ (((row >> 2) & 3) << 5));
            short8 z8 = *(const short8*)(zb + phys);
            *(short8*)(zout + (size_t)(row0 + s4 * 64 + row) * N_DIM + col0 + c8 * 8) = z8;
        }
        __syncthreads();
    }
}

// ---------- kernel 2b: streaming LN apply (mean/rstd from global sums) -------
__global__ __launch_bounds__(256) void ln_apply_kernel(
    const u16* __restrict__ z, const float* __restrict__ y,
    const float* __restrict__ stats, const float* __restrict__ gamma,
    const float* __restrict__ beta, float* __restrict__ out)
{
    int g   = blockIdx.x * 256 + threadIdx.x;
    int row = g >> 7;
    int c8  = g & 127;
    float s  = stats[row];
    float s2 = stats[16384 + row];
    float mean = s * (1.0f / 1024.0f);
    float var  = s2 * (1.0f / 1024.0f) - mean * mean;
    float rs   = rsqrtf(var + 1e-5f);
    short8 z8 = *(const short8*)(z + (size_t)row * N_DIM + c8 * 8);
    const float* yp  = y     + (size_t)row * N_DIM + c8 * 8;
    const float* gp  = gamma + c8 * 8;
    const float* bpv = beta  + c8 * 8;
    float*       op  = out   + (size_t)row * N_DIM + c8 * 8;
    floatx4 y0 = *(const floatx4*)(yp);
    floatx4 y1 = *(const floatx4*)(yp + 4);
    floatx4 g0 = *(const floatx4*)(gp);
    floatx4 g1 = *(const floatx4*)(gp + 4);
    floatx4 b0 = *(const floatx4*)(bpv);
    floatx4 b1 = *(const floatx4*)(bpv + 4);
    floatx4 o0, o1;
#pragma unroll
    for (int e = 0; e < 4; ++e) {
        float zv = b2f((u16)z8[e]);
        o0[e] = ((zv - mean) * rs * g0[e] + b0[e] + y0[e]) * y0[e];
    }
#pragma unroll
    for (int e = 0; e < 4; ++e) {
        float zv = b2f((u16)z8[e + 4]);
        o1[e] = ((zv - mean) * rs * g1[e] + b1[e] + y1[e]) * y1[e];
    }
    *(floatx4*)(op)     = o0;
    *(floatx4*)(op + 4) = o1;
}

// ---------- fallback: verified R6 fused kernel (workspace too small) ---------
__global__ __launch_bounds__(1024) void fused_gemm_ln_kernel(
    const float* __restrict__ x, const float* __restrict__ y,
    const u16* __restrict__ wpk, const float* __restrict__ bias,
    const float* __restrict__ gamma, const float* __restrict__ beta,
    float* __restrict__ out)
{
    __shared__ __align__(16) u16 lds16[HCHUNK * BM * BK];
    __shared__ __align__(16) u16 zbuf[16 * 1024];
    __shared__ float ls_sum[64];
    __shared__ float ls_sum2[64];
    __shared__ float ls_mean[64];
    __shared__ float ls_rs[64];

    const int tid  = threadIdx.x;
    const int lane = tid & 63;
    const int wv   = tid >> 6;
    const int q    = lane >> 4;
    const int row0 = blockIdx.x * BM;

    if (tid < 64) { ls_sum[tid] = 0.0f; ls_sum2[tid] = 0.0f; }

    const int sr = tid >> 4;
    const int sk = (tid & 15) << 1;
    const float* s_src = x + (size_t)(row0 + sr) * K_DIM + sk;
    const int s_qs  = (sk >> 3) ^ ((sr >> 1) & 3);
    const int s_off = sr * 64 + s_qs * 16 + (sk & 7) * 2;

    const u16* bp = wpk + (size_t)wv * 65536 + lane * 8;
    const int a_base = (lane & 15) * 64 + (q ^ (((lane & 15) >> 1) & 3)) * 16;

    floatx4 acc[4][4];
#pragma unroll
    for (int mi = 0; mi < 4; ++mi)
#pragma unroll
        for (int ni = 0; ni < 4; ++ni)
            acc[mi][ni] = (floatx4){0.0f, 0.0f, 0.0f, 0.0f};

#pragma unroll 4
    for (int c = 0; c < HCHUNK; ++c) {
        floatx2 v = *(const floatx2*)(s_src + c * BK);
        uint32_t p = (uint32_t)f2b(v[0]) | ((uint32_t)f2b(v[1]) << 16);
        *(uint32_t*)((char*)lds16 + c * 4096 + s_off) = p;
    }
    short8 bfr[2][4];
#pragma unroll
    for (int ni = 0; ni < 4; ++ni)
        bfr[0][ni] = *(const short8*)(bp + ni * 16384);
    __syncthreads();

    for (int half = 0; half < 2; ++half) {
        if (half == 1) {
            __syncthreads();
#pragma unroll 4
            for (int c = 0; c < HCHUNK; ++c) {
                floatx2 v = *(const floatx2*)(s_src + (HCHUNK + c) * BK);
                uint32_t p = (uint32_t)f2b(v[0]) | ((uint32_t)f2b(v[1]) << 16);
                *(uint32_t*)((char*)lds16 + c * 4096 + s_off) = p;
            }
            __syncthreads();
        }
#pragma unroll 2
        for (int c = 0; c < HCHUNK; ++c) {
            const int kc  = half * HCHUNK + c;
            const int cur = kc & 1;
            const int nxt = cur ^ 1;
            const char* ab = (const char*)lds16 + c * 4096;
            short8 af0 = *(const short8*)(ab + a_base);
            short8 af1 = *(const short8*)(ab + a_base + 1024);
            short8 af2 = *(const short8*)(ab + a_base + 2048);
            short8 af3 = *(const short8*)(ab + a_base + 3072);
            const int kn = (kc + 1 < NCHUNK) ? (kc + 1) : kc;
#pragma unroll
            for (int ni = 0; ni < 4; ++ni)
                bfr[nxt][ni] = *(const short8*)(bp + ni * 16384 + kn * 512);
#pragma unroll
            for (int ni = 0; ni < 4; ++ni) {
                acc[0][ni] = __builtin_amdgcn_mfma_f32_16x16x32_bf16(af0, bfr[cur][ni], acc[0][ni], 0, 0, 0);
                acc[1][ni] = __builtin_amdgcn_mfma_f32_16x16x32_bf16(af1, bfr[cur][ni], acc[1][ni], 0, 0, 0);
                acc[2][ni] = __builtin_amdgcn_mfma_f32_16x16x32_bf16(af2, bfr[cur][ni], acc[2][ni], 0, 0, 0);
                acc[3][ni] = __builtin_amdgcn_mfma_f32_16x16x32_bf16(af3, bfr[cur][ni], acc[3][ni], 0, 0, 0);
            }
        }
    }

    float bias_v[4];
#pragma unroll
    for (int ni = 0; ni < 4; ++ni)
        bias_v[ni] = bias[(wv << 6) + (ni << 4) + (lane & 15)];
#pragma unroll
    for (int mi = 0; mi < 4; ++mi)
#pragma unroll
        for (int ni = 0; ni < 4; ++ni)
#pragma unroll
            for (int r = 0; r < 4; ++r)
                acc[mi][ni][r] += bias_v[ni];

    __syncthreads();

#pragma unroll
    for (int mi = 0; mi < 4; ++mi)
#pragma unroll
        for (int r = 0; r < 4; ++r) {
            float s = 0.0f, s2 = 0.0f;
#pragma unroll
            for (int ni = 0; ni < 4; ++ni) {
                float v = acc[mi][ni][r];
                s += v; s2 += v * v;
            }
#pragma unroll
            for (int m = 1; m < 16; m <<= 1) {
                s  += __shfl_xor(s,  m, 64);
                s2 += __shfl_xor(s2, m, 64);
            }
            if ((lane & 15) == 0) {
                int rl = (mi << 4) + (q << 2) + r;
                atomicAdd(&ls_sum[rl], s);
                atomicAdd(&ls_sum2[rl], s2);
            }
        }

    __syncthreads();
    if (tid < 64) {
        float mean = ls_sum[tid] * (1.0f / 1024.0f);
        float var  = ls_sum2[tid] * (1.0f / 1024.0f) - mean * mean;
        ls_mean[tid] = mean;
        ls_rs[tid]   = rsqrtf(var + 1e-5f);
    }

    for (int mi = 0; mi < 4; ++mi) {
#pragma unroll
        for (int ni = 0; ni < 4; ++ni)
#pragma unroll
            for (int r = 0; r < 4; ++r) {
                int lr   = (q << 2) + r;
                int lin  = (((wv << 6) + (ni << 4) + (lane & 15)) << 1);
                int phys = lr * 2048 + (lin ^ (q << 5));
                *(u16*)((char*)zbuf + phys) = f2b(acc[mi][ni][r]);
            }
        __syncthreads();
#pragma unroll
        for (int it = 0; it < 2; ++it) {
            int row  = (tid >> 7) + (it << 3);
            int c8   = tid & 127;
            int phys = row * 2048 + ((c8 << 4) ^ (((row >> 2) & 3) << 5));
            short8 z8 = *(const short8*)((const char*)zbuf + phys);
            int grow  = row0 + (mi << 4) + row;
            float mean = ls_mean[(mi << 4) + row];
            float rs   = ls_rs[(mi << 4) + row];
            const float* yp = y     + (size_t)grow * N_DIM + c8 * 8;
            const float* gp = gamma + c8 * 8;
            const float* bpv = beta + c8 * 8;
            float*       op = out   + (size_t)grow * N_DIM + c8 * 8;
            floatx4 y0 = *(const floatx4*)(yp);
            floatx4 y1 = *(const floatx4*)(yp + 4);
            floatx4 g0 = *(const floatx4*)(gp);
            floatx4 g1 = *(const floatx4*)(gp + 4);
            floatx4 b0 = *(const floatx4*)(bpv);
            floatx4 b1 = *(const floatx4*)(bpv + 4);
            floatx4 o0, o1;
#pragma unroll
            for (int e = 0; e < 4; ++e) {
                float zv = b2f((u16)z8[e]);
                o0[e] = ((zv - mean) * rs * g0[e] + b0[e] + y0[e]) * y0[e];
            }
#pragma unroll
            for (int e = 0; e < 4; ++e) {
                float zv = b2f((u16)z8[e + 4]);
                o1[e] = ((zv - mean) * rs * g1[e] + b1[e] + y1[e]) * y1[e];
            }
            *(floatx4*)(op)     = o0;
            *(floatx4*)(op + 4) = o1;
        }
        __syncthreads();
    }
}

extern "C" void kernel_launch(void* const* d_in, const int* in_sizes, int n_in,
                              void* d_out, int out_size, void* d_ws, size_t ws_size,
                              hipStream_t stream) {
    const float* x     = (const float*)d_in[0];
    const float* y     = (const float*)d_in[1];
    const float* wgt   = (const float*)d_in[2];
    const float* bias  = (const float*)d_in[3];
    const float* gamma = (const float*)d_in[4];
    const float* beta  = (const float*)d_in[5];
    float* out = (float*)d_out;

    u16* wpk = (u16*)d_ws;                               // 2MB packed bf16 W
    const size_t WPK_BYTES   = 2u * 1024u * 1024u;
    const size_t STATS_BYTES = 128u * 1024u;             // 2 x 16384 fp32 sums
    const size_t Z_BYTES     = 32u * 1024u * 1024u;      // 16384x1024 bf16
    const int M = in_sizes[0] / K_DIM;                   // 16384

    pack_w_kernel<<<512, 256, 0, stream>>>(wgt, wpk);

    if (ws_size >= WPK_BYTES + STATS_BYTES + Z_BYTES) {
        float* stats = (float*)((char*)d_ws + WPK_BYTES);
        u16*   zws   = (u16*)((char*)d_ws + WPK_BYTES + STATS_BYTES);
        hipMemsetAsync(stats, 0, STATS_BYTES, stream);
        gemm256_kernel<<<(M / 256) * 4, 512, 0, stream>>>(
            x, wpk, bias, zws, stats, stats + 16384);
        ln_apply_kernel<<<M * (N_DIM / 8) / 256, 256, 0, stream>>>(
            zws, y, stats, gamma, beta, out);
    } else {
        fused_gemm_ln_kernel<<<M / BM, 1024, 0, stream>>>(
            x, y, wpk, bias, gamma, beta, out);
    }
}